// Round 4
// baseline (107.988 us; speedup 1.0000x reference)
//
#include <hip/hip_runtime.h>
#include <math.h>

#define SEQ   2048
#define VOCAB 50000
#define EMBD  50
#define L1OUT 2054      // (2048+12) - 7 + 1
#define NTOK  2060      // padded-token index space i = 0..2059 (g = i-6)
#define DSTR  2064      // LDS row stride for Dv (SoA)

// ---- fallback prep (only if ws too small for D): Wm + zero acc/cnt --------
__global__ void __launch_bounds__(384)
prep_kernel(const float* __restrict__ W1, float* __restrict__ ws) {
    int t = threadIdx.x;
    if (t < 350) {
        float s = 0.f;
        #pragma unroll
        for (int c = 0; c < 6; ++c) s += W1[t * 6 + c];
        ws[t] = s * (1.0f / 6.0f);
    } else if (t < 354) {
        ws[t] = 0.f;                        // [350..352) pad, [352] acc, [353] cnt
    }
}

// ---- build_d (fused Wm): D[v][0..6] = dot(emb[v], Wm[kw]); zero acc/cnt ---
__global__ void __launch_bounds__(256)
build_d(const float* __restrict__ emb, const float* __restrict__ W1,
        float* __restrict__ D, float* __restrict__ acc, int* __restrict__ cnt) {
    __shared__ float wm[352];
    int t = threadIdx.x;
    for (int i = t; i < 350; i += 256) {
        float s = 0.f;
        #pragma unroll
        for (int c = 0; c < 6; ++c) s += W1[i * 6 + c];
        wm[i] = s * (1.0f / 6.0f);
    }
    if (blockIdx.x == 0 && t == 0) { *acc = 0.f; *cnt = 0; }
    __syncthreads();

    int v = blockIdx.x * 256 + t;
    if (v >= VOCAB) return;
    const float2* row = (const float2*)(emb + (size_t)v * EMBD);
    float d[7] = {0.f, 0.f, 0.f, 0.f, 0.f, 0.f, 0.f};
    for (int e = 0; e < 25; ++e) {
        float2 r = row[e];
        #pragma unroll
        for (int kw = 0; kw < 7; ++kw)
            d[kw] = fmaf(r.y, wm[kw * 50 + 2 * e + 1],
                    fmaf(r.x, wm[kw * 50 + 2 * e], d[kw]));
    }
    float4* out = (float4*)(D + (size_t)v * 8);
    out[0] = make_float4(d[0], d[1], d[2], d[3]);
    out[1] = make_float4(d[4], d[5], d[6], 0.f);
}

// ---- main: one block (512 thr) per batch; fused finalize via atomics ------
template<int USE_D>
__global__ void __launch_bounds__(512, 1)
dcnn_main(const int* __restrict__ x, const float* __restrict__ emb,
          const float* __restrict__ W1, const float* __restrict__ b1,
          const float* __restrict__ W2, const float* __restrict__ b2,
          const float* __restrict__ Wd, const float* __restrict__ bd,
          const float* __restrict__ Dtab, const float* __restrict__ wm,
          float* __restrict__ acc, int* __restrict__ cnt,
          float* __restrict__ out)
{
    __shared__ float Dv[7][DSTR];         // 57.8 KB SoA per-token dot values
    __shared__ float cand_v[64];
    __shared__ int   cand_i[64];
    __shared__ int   topi[8];
    __shared__ float part[240];
    __shared__ float s1p[16][6];
    __shared__ float out2[12][14];
    __shared__ float exc2[12];

    const int b   = blockIdx.x;
    const int tid = threadIdx.x;
    const int* xb = x + b * SEQ;

    // ---- gather per-token D rows into SoA LDS (L2-resident 1.6 MB table) ----
    for (int i = tid; i < NTOK; i += 512) {
        int g = i - 6;
        float d0 = 0.f, d1 = 0.f, d2 = 0.f, d3 = 0.f,
              d4 = 0.f, d5 = 0.f, d6 = 0.f;
        if (g >= 0 && g < SEQ) {
            int tok = xb[g];
            if (USE_D) {
                const float4* dp = (const float4*)(Dtab + (size_t)tok * 8);
                float4 lo = dp[0], hi = dp[1];
                d0 = lo.x; d1 = lo.y; d2 = lo.z; d3 = lo.w;
                d4 = hi.x; d5 = hi.y; d6 = hi.z;
            } else {
                const float2* row = (const float2*)(emb + (size_t)tok * EMBD);
                float dd[7] = {0.f, 0.f, 0.f, 0.f, 0.f, 0.f, 0.f};
                for (int e = 0; e < 25; ++e) {
                    float2 r = row[e];
                    #pragma unroll
                    for (int kw = 0; kw < 7; ++kw)
                        dd[kw] = fmaf(r.y, wm[kw * 50 + 2 * e + 1],
                                 fmaf(r.x, wm[kw * 50 + 2 * e], dd[kw]));
                }
                d0 = dd[0]; d1 = dd[1]; d2 = dd[2]; d3 = dd[3];
                d4 = dd[4]; d5 = dd[5]; d6 = dd[6];
            }
        }
        Dv[0][i] = d0; Dv[1][i] = d1; Dv[2][i] = d2; Dv[3][i] = d3;
        Dv[4][i] = d4; Dv[5][i] = d5; Dv[6][i] = d6;
    }
    __syncthreads();

    // ---- excitements in registers: slots k=0..4, position t = tid + 512k ----
    // (slot 4 valid only for tid<6 -> t = 2048..2053; same formula, so
    //  lower slot == lower index and tie semantics are preserved)
    float ev[5];
    #pragma unroll
    for (int k = 0; k < 4; ++k) {
        int t = tid + 512 * k;
        ev[k] = ((Dv[0][t] + Dv[1][t + 1]) + (Dv[2][t + 2] + Dv[3][t + 3]))
              + ((Dv[4][t + 4] + Dv[5][t + 5]) + Dv[6][t + 6]);
    }
    if (tid < 6) {
        int t = tid + 2048;
        ev[4] = ((Dv[0][t] + Dv[1][t + 1]) + (Dv[2][t + 2] + Dv[3][t + 3]))
              + ((Dv[4][t + 4] + Dv[5][t + 5]) + Dv[6][t + 6]);
    } else {
        ev[4] = -INFINITY;
    }

    // ---- per-wave top-8 (shuffle butterfly, in-register removal) ----
    const int wid  = tid >> 6;
    const int lane = tid & 63;
    #pragma unroll 1
    for (int r = 0; r < 8; ++r) {
        float bv = ev[0]; int bk = 0;
        #pragma unroll
        for (int k = 1; k < 5; ++k)
            if (ev[k] > bv) { bv = ev[k]; bk = k; }   // strict >: lower slot wins ties
        int bi = tid + 512 * bk;
        #pragma unroll
        for (int off = 1; off < 64; off <<= 1) {
            float ov = __shfl_xor(bv, off, 64);
            int   oi = __shfl_xor(bi, off, 64);
            if (ov > bv || (ov == bv && oi < bi)) { bv = ov; bi = oi; }
        }
        // removal (static slot indexing only)
        #pragma unroll
        for (int k = 0; k < 5; ++k)
            if (tid + 512 * k == bi) ev[k] = -INFINITY;
        if (lane == 0) { cand_v[wid * 8 + r] = bv; cand_i[wid * 8 + r] = bi; }
    }
    __syncthreads();

    // ---- wave 0 merges 8x8 candidates -> global top-8 ----
    if (tid < 64) {
        float cv = cand_v[tid];
        int   ci = cand_i[tid];
        #pragma unroll 1
        for (int r = 0; r < 8; ++r) {
            float bv = cv; int bi = ci;
            #pragma unroll
            for (int off = 1; off < 64; off <<= 1) {
                float ov = __shfl_xor(bv, off, 64);
                int   oi = __shfl_xor(bi, off, 64);
                if (ov > bv || (ov == bv && oi < bi)) { bv = ov; bi = oi; }
            }
            if (cv == bv && ci == bi) cv = -INFINITY;   // ci unique -> exact removal
            if (tid == 0) topi[r] = bi;
        }
    }
    __syncthreads();

    // ---- recompute full 6-channel conv1 at the 8 selected positions ----
    if (tid < 96) ((float*)s1p)[tid] = 0.f;      // zero padded stage-2 input
    if (tid < 240) {                             // (r, c, e-decile) partials
        int r = tid / 30, sub = tid - r * 30;
        int c = sub / 5,  eq  = sub - c * 5;
        int t = topi[r];
        float a2 = 0.f;
        #pragma unroll
        for (int kw = 0; kw < 7; ++kw) {
            int g = t + kw - 6;
            if (g >= 0 && g < SEQ) {
                const float* row = emb + (size_t)xb[g] * EMBD + eq * 10;
                const float* wp  = W1 + (kw * 50 + eq * 10) * 6 + c;
                #pragma unroll
                for (int e = 0; e < 10; ++e)
                    a2 = fmaf(row[e], wp[e * 6], a2);
            }
        }
        part[tid] = a2;
    }
    __syncthreads();
    if (tid < 48) {
        int r = tid / 6, c = tid - r * 6;
        float s = b1[c];
        #pragma unroll
        for (int eq = 0; eq < 5; ++eq) s += part[r * 30 + c * 5 + eq];
        s1p[4 + r][c] = 1.0f / (1.0f + expf(-s));    // sigmoid, rows 4..11
    }
    __syncthreads();

    // ---- conv2: [16][6] -> [12][14] ----
    if (tid < 168) {
        int t = tid / 14, c = tid - t * 14;
        float a2 = b2[c];
        #pragma unroll
        for (int kw = 0; kw < 5; ++kw)
            #pragma unroll
            for (int i = 0; i < 6; ++i)
                a2 = fmaf(s1p[t + kw][i], W2[(kw * 6 + i) * 14 + c], a2);
        out2[t][c] = a2;
    }
    __syncthreads();
    if (tid < 12) {
        float s = 0.f;
        #pragma unroll
        for (int c = 0; c < 14; ++c) s += out2[tid][c];
        exc2[tid] = s / 14.0f;
    }
    __syncthreads();

    // ---- top-4 + mean-pool + dense + fused batch-mean finalize ----
    if (tid == 0) {
        float evl[12];
        #pragma unroll
        for (int t = 0; t < 12; ++t) evl[t] = exc2[t];
        int sel[4];
        #pragma unroll 1
        for (int r = 0; r < 4; ++r) {
            float bv = -INFINITY; int bi = 0;
            #pragma unroll
            for (int t = 0; t < 12; ++t)
                if (evl[t] > bv) { bv = evl[t]; bi = t; }  // strict >: lower idx wins
            sel[r] = bi; evl[bi] = -INFINITY;
        }
        float dense = bd[0];
        #pragma unroll
        for (int c = 0; c < 14; ++c) {
            float pool = 0.25f * ((out2[sel[0]][c] + out2[sel[1]][c]) +
                                  (out2[sel[2]][c] + out2[sel[3]][c]));
            dense = fmaf(pool, Wd[c], dense);
        }
        atomicAdd(acc, dense);
        __threadfence();                       // release: acc visible before cnt
        int done = atomicAdd(cnt, 1);
        if (done == 255) {                     // last block finalizes
            __threadfence();                   // acquire
            float s = atomicAdd(acc, 0.0f);    // coherent read of full sum
            out[0] = 1.0f / (1.0f + expf(-s * (1.0f / 256.0f)));
        }
    }
}

extern "C" void kernel_launch(void* const* d_in, const int* in_sizes, int n_in,
                              void* d_out, int out_size, void* d_ws, size_t ws_size,
                              hipStream_t stream) {
    const int*   x   = (const int*)d_in[0];
    const float* emb = (const float*)d_in[1];
    const float* W1  = (const float*)d_in[2];
    const float* b1  = (const float*)d_in[3];
    const float* W2  = (const float*)d_in[4];
    const float* b2  = (const float*)d_in[5];
    const float* Wd  = (const float*)d_in[6];
    const float* bd  = (const float*)d_in[7];
    float* ws = (float*)d_ws;

    // D-path ws layout: [384 .. 384+400000) D, then acc (f32), cnt (i32)
    const size_t needD = (size_t)(384 + VOCAB * 8 + 8) * sizeof(float);

    if (ws_size >= needD) {
        float* D   = ws + 384;
        float* acc = D + VOCAB * 8;
        int*   cnt = (int*)(acc + 1);
        build_d<<<(VOCAB + 255) / 256, 256, 0, stream>>>(emb, W1, D, acc, cnt);
        dcnn_main<1><<<256, 512, 0, stream>>>(x, emb, W1, b1, W2, b2, Wd, bd,
                                              D, ws, acc, cnt, (float*)d_out);
    } else {
        // fallback: wm at ws[0..350), acc ws[352], cnt ws[353]
        float* acc = ws + 352;
        int*   cnt = (int*)(ws + 353);
        prep_kernel<<<1, 384, 0, stream>>>(W1, ws);
        dcnn_main<0><<<256, 512, 0, stream>>>(x, emb, W1, b1, W2, b2, Wd, bd,
                                              ws, ws, acc, cnt, (float*)d_out);
    }
}